// Round 6
// baseline (248.562 us; speedup 1.0000x reference)
//
#include <hip/hip_runtime.h>

#define NB 8
#define NC 2048
#define KIN 128
#define NF 64

#define WTSTRIDE 136          // k1 LDS W^T row stride (ushorts)
#define MROW 272              // k2 LDS mask row stride (bytes, 16B-aligned)
#define MOFF 60.0f            // softmax shift slack: p <= e^60
#define LOG2E 1.44269504088896340736f

typedef float floatx4_t __attribute__((ext_vector_type(4)));
typedef __bf16 bf16x8_t __attribute__((ext_vector_type(8)));
typedef unsigned short ushort8_t __attribute__((ext_vector_type(8)));

static __device__ __forceinline__ unsigned short f2bf(float f) {
  union { float f; unsigned int u; } v; v.f = f;
  unsigned int u = v.u;
  u += 0x7FFFu + ((u >> 16) & 1u);   // RNE; inputs never NaN
  return (unsigned short)(u >> 16);
}

static __device__ __forceinline__ float lrelu(float x) {
  return fmaxf(x, 0.2f * x);
}

// ---------------------------------------------------------------------------
// Kernel 0: A (134 MB int32) -> row-major bitmask (4 MB), diagonal folded.
// One wave per row; 8 independent dwordx4 loads in flight before consumption.
// ---------------------------------------------------------------------------
__global__ __launch_bounds__(256, 4) void k0_mask(
    const int* __restrict__ A, unsigned char* __restrict__ maskG)
{
  const int wv = blockIdx.x * 4 + (threadIdx.x >> 6);   // row id in [0, NB*NC)
  const int lane = threadIdx.x & 63;
  const int r = wv & (NC - 1);                          // row within batch
  const int* arow = A + (size_t)wv * NC;

  int4 v[8];
#pragma unroll
  for (int s = 0; s < 4; ++s) {
    const int cbase = s * 512 + lane * 8;
    v[2 * s]     = *(const int4*)(arow + cbase);
    v[2 * s + 1] = *(const int4*)(arow + cbase + 4);
  }

  unsigned char* mrow = maskG + (size_t)wv * 256;
#pragma unroll
  for (int s = 0; s < 4; ++s) {
    const int cbase = s * 512 + lane * 8;
    const int4 a0 = v[2 * s];
    const int4 a1 = v[2 * s + 1];
    unsigned int byte = 0;
    byte |= (a0.x > 0 || cbase + 0 == r) ? 1u : 0u;
    byte |= (a0.y > 0 || cbase + 1 == r) ? 2u : 0u;
    byte |= (a0.z > 0 || cbase + 2 == r) ? 4u : 0u;
    byte |= (a0.w > 0 || cbase + 3 == r) ? 8u : 0u;
    byte |= (a1.x > 0 || cbase + 4 == r) ? 16u : 0u;
    byte |= (a1.y > 0 || cbase + 5 == r) ? 32u : 0u;
    byte |= (a1.z > 0 || cbase + 6 == r) ? 64u : 0u;
    byte |= (a1.w > 0 || cbase + 7 == r) ? 128u : 0u;
    mrow[s * 64 + lane] = (unsigned char)byte;
  }
}

// ---------------------------------------------------------------------------
// Kernel 1: per block = 16 c-rows of one batch. s1/s2 fp32-exact + WhT in
// MFMA-B-fragment-tiled layout: WhT3[b][w][kt][q*16+fs][j] (2 MB) so k2's
// per-wave fragment load is one contiguous 1 KB dwordx4 stream.
// ---------------------------------------------------------------------------
__global__ __launch_bounds__(256, 4) void k1_prep(
    const float* __restrict__ H, const float* __restrict__ W,
    const float* __restrict__ avec,
    float* __restrict__ s1g, float* __restrict__ s2g,
    unsigned short* __restrict__ WhT3)
{
  __shared__ unsigned short WTsh[NF * WTSTRIDE];   // 17.4 KB
  __shared__ float w1sh[KIN];
  __shared__ float w2sh[KIN];

  const int t = threadIdx.x;
  const int b = blockIdx.x >> 7;
  const int c0 = (blockIdx.x & 127) * 16;

  for (int i = t; i < KIN * NF; i += 256) {
    int k = i >> 6, f = i & 63;
    WTsh[f * WTSTRIDE + k] = f2bf(W[i]);
  }
  if (t < KIN) {
    float acc1 = 0.f, acc2 = 0.f;
    const float* wr = W + t * NF;
#pragma unroll
    for (int f = 0; f < NF; ++f) {
      float wv = wr[f];
      acc1 += wv * avec[f];
      acc2 += wv * avec[NF + f];
    }
    w1sh[t] = acc1;
    w2sh[t] = acc2;
  }
  __syncthreads();

  // s1/s2: 16 threads per row, 8 cols each
  {
    const int r = t >> 4;
    const int x = t & 15;
    const float* hp = H + (size_t)(b * NC + c0 + r) * KIN + x * 8;
    float4 h0 = *(const float4*)(hp);
    float4 h1 = *(const float4*)(hp + 4);
    float4 u10 = *(const float4*)(w1sh + x * 8);
    float4 u11 = *(const float4*)(w1sh + x * 8 + 4);
    float4 u20 = *(const float4*)(w2sh + x * 8);
    float4 u21 = *(const float4*)(w2sh + x * 8 + 4);
    float p1 = h0.x * u10.x + h0.y * u10.y + h0.z * u10.z + h0.w * u10.w
             + h1.x * u11.x + h1.y * u11.y + h1.z * u11.z + h1.w * u11.w;
    float p2 = h0.x * u20.x + h0.y * u20.y + h0.z * u20.z + h0.w * u20.w
             + h1.x * u21.x + h1.y * u21.y + h1.z * u21.z + h1.w * u21.w;
#pragma unroll
    for (int off = 1; off < 16; off <<= 1) {
      p1 += __shfl_xor(p1, off);
      p2 += __shfl_xor(p2, off);
    }
    if (x == 0) {
      s1g[b * NC + c0 + r] = p1;
      s2g[b * NC + c0 + r] = p2;
    }
  }

  // MFMA: D = W^T · H^T; wave w owns f rows w*16..w*16+15
  const int wave = t >> 6;
  const int lane = t & 63;
  const int m = lane & 15;   // c sub-index
  const int q = lane >> 4;   // f quad
  floatx4_t acc = (floatx4_t){0.f, 0.f, 0.f, 0.f};

  const float* hb = H + (size_t)(b * NC + c0 + m) * KIN;
#pragma unroll
  for (int kt = 0; kt < 4; ++kt) {
    const int kbase = kt * 32 + q * 8;
    float4 h0 = *(const float4*)(hb + kbase);
    float4 h1 = *(const float4*)(hb + kbase + 4);
    ushort8_t bu;
    bu[0] = f2bf(h0.x); bu[1] = f2bf(h0.y); bu[2] = f2bf(h0.z); bu[3] = f2bf(h0.w);
    bu[4] = f2bf(h1.x); bu[5] = f2bf(h1.y); bu[6] = f2bf(h1.z); bu[7] = f2bf(h1.w);
    bf16x8_t bf = __builtin_bit_cast(bf16x8_t, bu);
    ushort8_t au = *(const ushort8_t*)(WTsh + (wave * 16 + m) * WTSTRIDE + kbase);
    bf16x8_t af = __builtin_bit_cast(bf16x8_t, au);
    acc = __builtin_amdgcn_mfma_f32_16x16x32_bf16(af, bf, acc, 0, 0, 0);
  }
  // element (f = wave*16 + q*4+i2, c = c0+m) -> WhT3[b][wave][c>>5][(c>>3)&3][fs][c&7]
  {
    const int c = c0 + m;
    const int ktc = c >> 5, q2 = (c >> 3) & 3, j = c & 7;
    unsigned short* base =
        WhT3 + ((((size_t)(b * 4 + wave) * 64 + ktc) * 4 + q2) * 16) * 8 + j;
#pragma unroll
    for (int i2 = 0; i2 < 4; ++i2)
      base[(q * 4 + i2) * 8] = f2bf(acc[i2]);
  }
}

// ---------------------------------------------------------------------------
// Kernel 2: per block = 32 query rows (512 blocks). Waves split the f
// dimension (wave w owns f-tile w): no cross-wave reduce, no red_sh, single
// barrier. WhT3 read as a contiguous per-wave 1 KB/iter stream, depth-4
// register prefetch. Denominators via ones-column MFMA per wave.
// ---------------------------------------------------------------------------
__global__ __launch_bounds__(256, 2) void k2_attn(
    const unsigned char* __restrict__ maskG, const float* __restrict__ s1g,
    const float* __restrict__ s2g, const unsigned short* __restrict__ WhT3,
    float* __restrict__ out)
{
  __shared__ float s2_sh[NC];                   // 8 KB
  __shared__ unsigned char mask_sh[32 * MROW];  // 8.7 KB
  __shared__ float s1_sh[32];
  __shared__ float wmax_sh[4];
  __shared__ float lsum_sh[4 * 32];             // per-wave row sums

  const int t = threadIdx.x;
  const int b = blockIdx.x >> 6;
  const int i0 = (blockIdx.x & 63) * 32;
  const int wave = t >> 6;
  const int lane = t & 63;

  // stage s2 + batch max of s2
  float lmax;
  {
    const float* sp = s2g + b * NC;
    float4 v0 = *(const float4*)(sp + t * 4);
    float4 v1 = *(const float4*)(sp + 1024 + t * 4);
    *(float4*)(s2_sh + t * 4) = v0;
    *(float4*)(s2_sh + 1024 + t * 4) = v1;
    lmax = fmaxf(fmaxf(fmaxf(v0.x, v0.y), fmaxf(v0.z, v0.w)),
                 fmaxf(fmaxf(v1.x, v1.y), fmaxf(v1.z, v1.w)));
#pragma unroll
    for (int off = 1; off < 64; off <<= 1)
      lmax = fmaxf(lmax, __shfl_xor(lmax, off));
    if (lane == 0) wmax_sh[wave] = lmax;
  }
  if (t < 32) s1_sh[t] = s1g[b * NC + i0 + t];

  // stage bitmask rows (32 x 256 B)
  {
    const int row = t >> 3;
    const int off = (t & 7) * 32;
    const unsigned char* src = maskG + (size_t)(b * NC + i0 + row) * 256 + off;
    *(uint4*)(mask_sh + row * MROW + off) = *(const uint4*)(src);
    *(uint4*)(mask_sh + row * MROW + off + 16) = *(const uint4*)(src + 16);
  }
  __syncthreads();

  const float s2max =
      fmaxf(fmaxf(wmax_sh[0], wmax_sh[1]), fmaxf(wmax_sh[2], wmax_sh[3]));

  const int m = lane & 15;   // A-frag row sub / C col sub
  const int q = lane >> 4;
  const float s1A = s1_sh[m];
  const float s1B = s1_sh[16 + m];
  const float mmLA = (lrelu(s1A + s2max) - MOFF) * LOG2E;
  const float mmLB = (lrelu(s1B + s2max) - MOFF) * LOG2E;

  // ones B-fragment: column 0 = 1.0 -> acc col0 = row sums of P
  ushort8_t ou;
  {
    const unsigned short ov = (m == 0) ? (unsigned short)0x3F80 : (unsigned short)0;
#pragma unroll
    for (int idx = 0; idx < 8; ++idx) ou[idx] = ov;
  }
  const bf16x8_t onesf = __builtin_bit_cast(bf16x8_t, ou);

  floatx4_t accA = {0.f, 0.f, 0.f, 0.f}, accB = {0.f, 0.f, 0.f, 0.f};
  floatx4_t acclA = {0.f, 0.f, 0.f, 0.f}, acclB = {0.f, 0.f, 0.f, 0.f};

  // WhT3 stream for this wave's f-tile: contiguous 1 KB per kt
  const unsigned short* wstream =
      WhT3 + ((size_t)(b * 4 + wave) * 64) * 512 + (size_t)lane * 8;
  ushort8_t wbuf[4];
#pragma unroll
  for (int i = 0; i < 4; ++i)
    wbuf[i] = *(const ushort8_t*)(wstream + i * 512);

#pragma unroll 4
  for (int kt = 0; kt < 64; ++kt) {
    const ushort8_t wcur = wbuf[kt & 3];
    if (kt + 4 < 64)
      wbuf[kt & 3] = *(const ushort8_t*)(wstream + (kt + 4) * 512);

    const int jq = kt * 32 + q * 8;
    const unsigned int mbA = mask_sh[m * MROW + kt * 4 + q];
    const unsigned int mbB = mask_sh[(m + 16) * MROW + kt * 4 + q];
    float4 s0 = *(const float4*)(s2_sh + jq);
    float4 s1v = *(const float4*)(s2_sh + jq + 4);
    const float sv[8] = {s0.x, s0.y, s0.z, s0.w, s1v.x, s1v.y, s1v.z, s1v.w};

    uint4 pkA, pkB;
#pragma unroll
    for (int pair = 0; pair < 4; ++pair) {
      float a0 = __builtin_amdgcn_exp2f(
          fmaf(lrelu(s1A + sv[2 * pair]), LOG2E, -mmLA));
      float a1 = __builtin_amdgcn_exp2f(
          fmaf(lrelu(s1A + sv[2 * pair + 1]), LOG2E, -mmLA));
      float b0 = __builtin_amdgcn_exp2f(
          fmaf(lrelu(s1B + sv[2 * pair]), LOG2E, -mmLB));
      float b1 = __builtin_amdgcn_exp2f(
          fmaf(lrelu(s1B + sv[2 * pair + 1]), LOG2E, -mmLB));
      a0 = (mbA & (1u << (2 * pair))) ? a0 : 0.0f;
      a1 = (mbA & (2u << (2 * pair))) ? a1 : 0.0f;
      b0 = (mbB & (1u << (2 * pair))) ? b0 : 0.0f;
      b1 = (mbB & (2u << (2 * pair))) ? b1 : 0.0f;
      pkA[pair] = __builtin_amdgcn_perm(__builtin_bit_cast(unsigned int, a1),
                                        __builtin_bit_cast(unsigned int, a0),
                                        0x07060302u);
      pkB[pair] = __builtin_amdgcn_perm(__builtin_bit_cast(unsigned int, b1),
                                        __builtin_bit_cast(unsigned int, b0),
                                        0x07060302u);
    }
    const bf16x8_t afA = __builtin_bit_cast(bf16x8_t, pkA);
    const bf16x8_t afB = __builtin_bit_cast(bf16x8_t, pkB);
    const bf16x8_t bfc = __builtin_bit_cast(bf16x8_t, wcur);
    accA = __builtin_amdgcn_mfma_f32_16x16x32_bf16(afA, bfc, accA, 0, 0, 0);
    acclA = __builtin_amdgcn_mfma_f32_16x16x32_bf16(afA, onesf, acclA, 0, 0, 0);
    accB = __builtin_amdgcn_mfma_f32_16x16x32_bf16(afB, bfc, accB, 0, 0, 0);
    acclB = __builtin_amdgcn_mfma_f32_16x16x32_bf16(afB, onesf, acclB, 0, 0, 0);
  }

  // per-wave row sums -> LDS (wave-private, intra-wave visibility via lgkmcnt)
  if (m == 0) {
#pragma unroll
    for (int i2 = 0; i2 < 4; ++i2) {
      lsum_sh[wave * 32 + q * 4 + i2] = acclA[i2];
      lsum_sh[wave * 32 + 16 + q * 4 + i2] = acclB[i2];
    }
  }

  // epilogue: out[row, wave*16 + m]; C-layout row = q*4+i2, col = m
#pragma unroll
  for (int i2 = 0; i2 < 4; ++i2) {
    const float invA = 1.0f / lsum_sh[wave * 32 + q * 4 + i2];
    const float invB = 1.0f / lsum_sh[wave * 32 + 16 + q * 4 + i2];
    out[(size_t)(b * NC + i0 + q * 4 + i2) * NF + wave * 16 + m] =
        fmaxf(accA[i2] * invA, 0.f);
    out[(size_t)(b * NC + i0 + 16 + q * 4 + i2) * NF + wave * 16 + m] =
        fmaxf(accB[i2] * invB, 0.f);
  }
}

extern "C" void kernel_launch(void* const* d_in, const int* in_sizes, int n_in,
                              void* d_out, int out_size, void* d_ws, size_t ws_size,
                              hipStream_t stream) {
  const float* H = (const float*)d_in[0];
  const int* A = (const int*)d_in[1];
  const float* W = (const float*)d_in[2];
  const float* avec = (const float*)d_in[3];
  float* out = (float*)d_out;

  char* ws = (char*)d_ws;
  unsigned short* WhT3 = (unsigned short*)ws;                       // 2 MB
  float* s1 = (float*)(ws + (size_t)NB * NF * NC * 2);              // 64 KB
  float* s2 = s1 + NB * NC;                                         // 64 KB
  unsigned char* maskG = (unsigned char*)(s2 + NB * NC);            // 4 MB

  k0_mask<<<dim3(NB * NC / 4), dim3(256), 0, stream>>>(A, maskG);
  k1_prep<<<dim3(NB * (NC / 16)), dim3(256), 0, stream>>>(H, W, avec, s1, s2, WhT3);
  k2_attn<<<dim3(NB * (NC / 32)), dim3(256), 0, stream>>>(maskG, s1, s2, WhT3, out);
}